// Round 1
// baseline (1187.062 us; speedup 1.0000x reference)
//
#include <hip/hip_runtime.h>
#include <hip/hip_bf16.h>
#include <math.h>

#define IN_DIM 128
#define OUT_DIM 64
#define NHEAD 4
#define HDIM 16
#define TEMP_INV 2.0f
#define NEG_SLOPE 0.01f

// K1: mask = softmax((logits+gumbel)/TEMP); Wp = diag(mask) @ W   [128x64]
__global__ void k_mask_w(const float* __restrict__ logits, const float* __restrict__ gumbel,
                         const float* __restrict__ W, float* __restrict__ Wp) {
    __shared__ float sh[IN_DIM];
    int t = threadIdx.x;              // 128 threads
    float v = (logits[t] + gumbel[t]) * TEMP_INV;
    sh[t] = v;
    __syncthreads();
    float m = -INFINITY;
    for (int i = 0; i < IN_DIM; ++i) m = fmaxf(m, sh[i]);
    float e = __expf(v - m);
    __syncthreads();
    sh[t] = e;
    __syncthreads();
    float sum = 0.f;
    for (int i = 0; i < IN_DIM; ++i) sum += sh[i];
    float mask = e / sum;
    __syncthreads();
    sh[t] = mask;
    __syncthreads();
    for (int idx = t; idx < IN_DIM * OUT_DIM; idx += blockDim.x)
        Wp[idx] = sh[idx >> 6] * W[idx];
}

// init smax to -inf, denom to 0 (ws is poisoned 0xAA every call)
__global__ void k_init(unsigned* __restrict__ smax_bits, float* __restrict__ denom, int n4) {
    int i = blockIdx.x * blockDim.x + threadIdx.x;
    if (i < n4) { smax_bits[i] = 0xFF800000u; denom[i] = 0.f; }
}

// K2: h = feat @ Wp (N x 64); epilogue: asrc[n][h], adst[n][h] head-dot products.
// One wave per row, lane = output column j (= head*16 + d).
__global__ void k_gemm(const float* __restrict__ feat, const float* __restrict__ Wp,
                       const float* __restrict__ attn_w, float* __restrict__ h,
                       float* __restrict__ asrc, float* __restrict__ adst, int nRows) {
    __shared__ float sW[IN_DIM * OUT_DIM];   // 32 KB
    __shared__ float sA[NHEAD * 2 * HDIM];   // 512 B
    for (int i = threadIdx.x; i < IN_DIM * OUT_DIM; i += blockDim.x) sW[i] = Wp[i];
    for (int i = threadIdx.x; i < NHEAD * 2 * HDIM; i += blockDim.x) sA[i] = attn_w[i];
    __syncthreads();

    int wave = threadIdx.x >> 6;
    int lane = threadIdx.x & 63;
    int head = lane >> 4, d = lane & 15;
    float aw_s = sA[head * 2 * HDIM + d];
    float aw_d = sA[head * 2 * HDIM + HDIM + d];

    for (int row = blockIdx.x * 4 + wave; row < nRows; row += gridDim.x * 4) {
        const float4* frow = (const float4*)(feat + (size_t)row * IN_DIM);
        float acc = 0.f;
        #pragma unroll 8
        for (int k4 = 0; k4 < IN_DIM / 4; ++k4) {
            float4 f = frow[k4];               // uniform across lanes -> broadcast
            acc += f.x * sW[(k4 * 4 + 0) * OUT_DIM + lane];
            acc += f.y * sW[(k4 * 4 + 1) * OUT_DIM + lane];
            acc += f.z * sW[(k4 * 4 + 2) * OUT_DIM + lane];
            acc += f.w * sW[(k4 * 4 + 3) * OUT_DIM + lane];
        }
        h[(size_t)row * OUT_DIM + lane] = acc;
        // per-head dot with attn_w halves: reduce within each 16-lane group
        float v1 = acc * aw_s;
        float v2 = acc * aw_d;
        #pragma unroll
        for (int off = 1; off < HDIM; off <<= 1) {
            v1 += __shfl_xor(v1, off, 64);
            v2 += __shfl_xor(v2, off, 64);
        }
        if (d == 0) {
            asrc[(size_t)row * NHEAD + head] = v1;
            adst[(size_t)row * NHEAD + head] = v2;
        }
    }
}

__device__ inline void atomicMaxF(float* addr, float v) {
    // valid because ordering of ints matches floats for >=0, reversed (as uint) for <0
    if (v >= 0.f) atomicMax((int*)addr, __float_as_int(v));
    else          atomicMin((unsigned int*)addr, __float_as_uint(v));
}

__device__ inline float lrelu(float x) { return x >= 0.f ? x : NEG_SLOPE * x; }

// K3: per-edge scores -> segment max via atomics. Thread per edge, 4 heads via float4 gathers.
__global__ void k_smax(const int* __restrict__ src, const int* __restrict__ dst,
                       const float4* __restrict__ asrc, const float4* __restrict__ adst,
                       float* __restrict__ smax, int nE) {
    int e = blockIdx.x * blockDim.x + threadIdx.x;
    if (e >= nE) return;
    int s = src[e], d = dst[e];
    float4 A = asrc[s], B = adst[d];
    float x0 = lrelu(A.x + B.x), x1 = lrelu(A.y + B.y);
    float x2 = lrelu(A.z + B.z), x3 = lrelu(A.w + B.w);
    atomicMaxF(&smax[d * 4 + 0], x0);
    atomicMaxF(&smax[d * 4 + 1], x1);
    atomicMaxF(&smax[d * 4 + 2], x2);
    atomicMaxF(&smax[d * 4 + 3], x3);
}

// K4: denom = segment_sum(exp(s - smax[dst]))
__global__ void k_denom(const int* __restrict__ src, const int* __restrict__ dst,
                        const float4* __restrict__ asrc, const float4* __restrict__ adst,
                        const float4* __restrict__ smax4, float* __restrict__ denom, int nE) {
    int e = blockIdx.x * blockDim.x + threadIdx.x;
    if (e >= nE) return;
    int s = src[e], d = dst[e];
    float4 A = asrc[s], B = adst[d], M = smax4[d];
    atomicAdd(&denom[d * 4 + 0], __expf(lrelu(A.x + B.x) - M.x));
    atomicAdd(&denom[d * 4 + 1], __expf(lrelu(A.y + B.y) - M.y));
    atomicAdd(&denom[d * 4 + 2], __expf(lrelu(A.z + B.z) - M.z));
    atomicAdd(&denom[d * 4 + 3], __expf(lrelu(A.w + B.w) - M.w));
}

// K5: out[dst] += a * h[src]. One wave per edge; lane = output column.
__global__ void k_scatter(const int* __restrict__ src, const int* __restrict__ dst,
                          const float* __restrict__ asrc, const float* __restrict__ adst,
                          const float* __restrict__ smax, const float* __restrict__ denom,
                          const float* __restrict__ h, float* __restrict__ out, int nE) {
    int gw = (int)(((size_t)blockIdx.x * blockDim.x + threadIdx.x) >> 6);
    int lane = threadIdx.x & 63;
    if (gw >= nE) return;
    int s = src[gw], d = dst[gw];
    int head = lane >> 4;
    float sc = lrelu(asrc[s * 4 + head] + adst[d * 4 + head]);
    float ex = __expf(sc - smax[d * 4 + head]);
    float a = ex / denom[d * 4 + head];
    float hv = h[(size_t)s * OUT_DIM + lane];
    atomicAdd(&out[(size_t)d * OUT_DIM + lane], hv * a);
}

extern "C" void kernel_launch(void* const* d_in, const int* in_sizes, int n_in,
                              void* d_out, int out_size, void* d_ws, size_t ws_size,
                              hipStream_t stream) {
    const float* feat   = (const float*)d_in[0];
    const int*   src    = (const int*)  d_in[1];
    const int*   dst    = (const int*)  d_in[2];
    const float* gumbel = (const float*)d_in[3];
    const float* logits = (const float*)d_in[4];
    const float* W      = (const float*)d_in[5];
    const float* attn_w = (const float*)d_in[6];
    float* out = (float*)d_out;

    int N = in_sizes[0] / IN_DIM;
    int E = in_sizes[1];

    float* ws    = (float*)d_ws;
    float* Wp    = ws;                              // 128*64
    float* h     = Wp + IN_DIM * OUT_DIM;           // N*64
    float* asrc  = h + (size_t)N * OUT_DIM;         // N*4
    float* adst  = asrc + (size_t)N * NHEAD;        // N*4
    float* smax  = adst + (size_t)N * NHEAD;        // N*4
    float* denom = smax + (size_t)N * NHEAD;        // N*4

    hipMemsetAsync(d_out, 0, (size_t)N * OUT_DIM * sizeof(float), stream);
    k_mask_w<<<1, 128, 0, stream>>>(logits, gumbel, W, Wp);
    k_init<<<(N * NHEAD + 255) / 256, 256, 0, stream>>>((unsigned*)smax, denom, N * NHEAD);
    k_gemm<<<1024, 256, 0, stream>>>(feat, Wp, attn_w, h, asrc, adst, N);
    k_smax<<<(E + 255) / 256, 256, 0, stream>>>(src, dst, (const float4*)asrc,
                                                (const float4*)adst, smax, E);
    k_denom<<<(E + 255) / 256, 256, 0, stream>>>(src, dst, (const float4*)asrc,
                                                 (const float4*)adst, (const float4*)smax,
                                                 denom, E);
    long long t5 = (long long)E * 64;
    k_scatter<<<(int)((t5 + 255) / 256), 256, 0, stream>>>(src, dst, asrc, adst,
                                                           smax, denom, h, out, E);
}

// Round 3
// 645.667 us; speedup vs baseline: 1.8385x; 1.8385x over previous
//
#include <hip/hip_runtime.h>
#include <hip/hip_bf16.h>
#include <math.h>

#define IN_DIM 128
#define OUT_DIM 64
#define NHEAD 4
#define HDIM 16
#define TEMP_INV 2.0f
#define NEG_SLOPE 0.01f

// K1: mask = softmax((logits+gumbel)/TEMP); Wp = diag(mask) @ W   [128x64]
__global__ void k_mask_w(const float* __restrict__ logits, const float* __restrict__ gumbel,
                         const float* __restrict__ W, float* __restrict__ Wp) {
    __shared__ float sh[IN_DIM];
    int t = threadIdx.x;              // 128 threads
    float v = (logits[t] + gumbel[t]) * TEMP_INV;
    sh[t] = v;
    __syncthreads();
    float m = -INFINITY;
    for (int i = 0; i < IN_DIM; ++i) m = fmaxf(m, sh[i]);
    float e = __expf(v - m);
    __syncthreads();
    sh[t] = e;
    __syncthreads();
    float sum = 0.f;
    for (int i = 0; i < IN_DIM; ++i) sum += sh[i];
    float mask = e / sum;
    __syncthreads();
    sh[t] = mask;
    __syncthreads();
    for (int idx = t; idx < IN_DIM * OUT_DIM; idx += blockDim.x)
        Wp[idx] = sh[idx >> 6] * W[idx];
}

// K2: histogram of dst -> deg
__global__ void k_hist(const int* __restrict__ dst, int* __restrict__ deg, int nE) {
    int e = blockIdx.x * blockDim.x + threadIdx.x;
    if (e < nE) atomicAdd(&deg[dst[e]], 1);
}

// K3: single-block exclusive scan deg -> cursor (4 elements/thread, wave-shfl scan)
__global__ void k_scan(const int* __restrict__ deg, int* __restrict__ cursor, int n) {
    __shared__ int wsum[16];
    int t = threadIdx.x, lane = t & 63, wid = t >> 6;   // 1024 threads
    int base_acc = 0;
    for (int base = 0; base < n; base += 4096) {
        int i0 = base + t * 4;
        int a0 = (i0 + 0 < n) ? deg[i0 + 0] : 0;
        int a1 = (i0 + 1 < n) ? deg[i0 + 1] : 0;
        int a2 = (i0 + 2 < n) ? deg[i0 + 2] : 0;
        int a3 = (i0 + 3 < n) ? deg[i0 + 3] : 0;
        int s = a0 + a1 + a2 + a3;
        // inclusive wave scan of s
        int x = s;
        #pragma unroll
        for (int off = 1; off < 64; off <<= 1) {
            int y = __shfl_up(x, off, 64);
            if (lane >= off) x += y;
        }
        if (lane == 63) wsum[wid] = x;
        __syncthreads();
        int wbase = 0;
        for (int w = 0; w < wid; ++w) wbase += wsum[w];
        int tot = 0;
        for (int w = 0; w < 16; ++w) tot += wsum[w];
        int excl = base_acc + wbase + (x - s);
        if (i0 + 0 < n) cursor[i0 + 0] = excl;
        if (i0 + 1 < n) cursor[i0 + 1] = excl + a0;
        if (i0 + 2 < n) cursor[i0 + 2] = excl + a0 + a1;
        if (i0 + 3 < n) cursor[i0 + 3] = excl + a0 + a1 + a2;
        base_acc += tot;
        __syncthreads();
    }
}

// K4: fill CSR: csr_src[pos] = src[e], bucketed by dst. cursor ends at off[d+1].
__global__ void k_fill(const int* __restrict__ src, const int* __restrict__ dst,
                       int* __restrict__ cursor, int* __restrict__ csr_src, int nE) {
    int e = blockIdx.x * blockDim.x + threadIdx.x;
    if (e >= nE) return;
    int d = dst[e];
    int pos = atomicAdd(&cursor[d], 1);
    csr_src[pos] = src[e];
}

// K5: h = feat @ Wp; epilogue computes asrc/adst. 4 rows per wave (amortize LDS reads).
__global__ void k_gemm(const float* __restrict__ feat, const float* __restrict__ Wp,
                       const float* __restrict__ attn_w, float* __restrict__ h,
                       float* __restrict__ asrc, float* __restrict__ adst, int nRows) {
    __shared__ float sW[IN_DIM * OUT_DIM];   // 32 KB
    __shared__ float sA[NHEAD * 2 * HDIM];   // 512 B
    for (int i = threadIdx.x; i < IN_DIM * OUT_DIM; i += blockDim.x) sW[i] = Wp[i];
    if (threadIdx.x < NHEAD * 2 * HDIM) sA[threadIdx.x] = attn_w[threadIdx.x];
    __syncthreads();

    int wave = threadIdx.x >> 6;
    int lane = threadIdx.x & 63;
    int head = lane >> 4, d = lane & 15;
    float aw_s = sA[head * 2 * HDIM + d];
    float aw_d = sA[head * 2 * HDIM + HDIM + d];

    int row0 = (blockIdx.x * 4 + wave) * 4;          // 4 consecutive rows per wave
    if (row0 >= nRows) return;
    const float4* f = (const float4*)(feat + (size_t)row0 * IN_DIM);
    float acc0 = 0.f, acc1 = 0.f, acc2 = 0.f, acc3 = 0.f;
    #pragma unroll 4
    for (int k4 = 0; k4 < IN_DIM / 4; ++k4) {
        float4 fa = f[k4];
        float4 fb = f[32 + k4];
        float4 fc = f[64 + k4];
        float4 fd = f[96 + k4];
        float w0 = sW[(k4 * 4 + 0) * OUT_DIM + lane];
        float w1 = sW[(k4 * 4 + 1) * OUT_DIM + lane];
        float w2 = sW[(k4 * 4 + 2) * OUT_DIM + lane];
        float w3 = sW[(k4 * 4 + 3) * OUT_DIM + lane];
        acc0 += fa.x * w0 + fa.y * w1 + fa.z * w2 + fa.w * w3;
        acc1 += fb.x * w0 + fb.y * w1 + fb.z * w2 + fb.w * w3;
        acc2 += fc.x * w0 + fc.y * w1 + fc.z * w2 + fc.w * w3;
        acc3 += fd.x * w0 + fd.y * w1 + fd.z * w2 + fd.w * w3;
    }
    float accs[4] = {acc0, acc1, acc2, acc3};
    #pragma unroll
    for (int r = 0; r < 4; ++r) {
        int row = row0 + r;
        h[(size_t)row * OUT_DIM + lane] = accs[r];
        float v1 = accs[r] * aw_s;
        float v2 = accs[r] * aw_d;
        #pragma unroll
        for (int off = 1; off < HDIM; off <<= 1) {
            v1 += __shfl_xor(v1, off, 64);
            v2 += __shfl_xor(v2, off, 64);
        }
        if (d == 0) {
            asrc[(size_t)row * NHEAD + head] = v1;
            adst[(size_t)row * NHEAD + head] = v2;
        }
    }
}

// K6: fused per-dst-node: online softmax over incoming edges + weighted h gather.
// One wave per node; lane = output column.
__global__ void k_fused(const int* __restrict__ cursor, const int* __restrict__ csr_src,
                        const float* __restrict__ asrc, const float* __restrict__ adst,
                        const float* __restrict__ h, float* __restrict__ out, int nN) {
    int node = blockIdx.x * 4 + (threadIdx.x >> 6);
    if (node >= nN) return;
    int lane = threadIdx.x & 63;
    int head = lane >> 4;
    int start = (node == 0) ? 0 : cursor[node - 1];   // cursor[d] == off[d+1] after k_fill
    int end = cursor[node];
    float ad = adst[node * 4 + head];
    float m = -INFINITY, l = 0.f, acc = 0.f;
    for (int e = start; e < end; ++e) {
        int s = csr_src[e];
        float av = asrc[s * 4 + head];
        float hv = h[(size_t)s * OUT_DIM + lane];
        float x = av + ad;
        x = x >= 0.f ? x : NEG_SLOPE * x;
        float mn = fmaxf(m, x);
        float corr = __expf(m - mn);
        float p = __expf(x - mn);
        l = l * corr + p;
        acc = acc * corr + p * hv;
        m = mn;
    }
    out[(size_t)node * OUT_DIM + lane] = (end > start) ? acc / l : 0.f;
}

extern "C" void kernel_launch(void* const* d_in, const int* in_sizes, int n_in,
                              void* d_out, int out_size, void* d_ws, size_t ws_size,
                              hipStream_t stream) {
    const float* feat   = (const float*)d_in[0];
    const int*   src    = (const int*)  d_in[1];
    const int*   dst    = (const int*)  d_in[2];
    const float* gumbel = (const float*)d_in[3];
    const float* logits = (const float*)d_in[4];
    const float* W      = (const float*)d_in[5];
    const float* attn_w = (const float*)d_in[6];
    float* out = (float*)d_out;

    int N = in_sizes[0] / IN_DIM;
    int E = in_sizes[1];

    float* ws    = (float*)d_ws;
    float* Wp    = ws;                               // 8192 floats
    float* h     = Wp + IN_DIM * OUT_DIM;            // N*64
    float* asrc  = h + (size_t)N * OUT_DIM;          // N*4
    float* adst  = asrc + (size_t)N * NHEAD;         // N*4
    int*   deg    = (int*)(adst + (size_t)N * NHEAD); // N
    int*   cursor = deg + N;                          // N
    int*   csr    = cursor + N;                       // E

    hipMemsetAsync(deg, 0, (size_t)N * sizeof(int), stream);
    k_mask_w<<<1, 128, 0, stream>>>(logits, gumbel, W, Wp);
    k_hist<<<(E + 255) / 256, 256, 0, stream>>>(dst, deg, E);
    k_scan<<<1, 1024, 0, stream>>>(deg, cursor, N);
    k_fill<<<(E + 255) / 256, 256, 0, stream>>>(src, dst, cursor, csr, E);
    k_gemm<<<(N + 15) / 16, 256, 0, stream>>>(feat, Wp, attn_w, h, asrc, adst, N);
    k_fused<<<(N + 3) / 4, 256, 0, stream>>>(cursor, csr, asrc, adst, h, out, N);
}

// Round 5
// 528.449 us; speedup vs baseline: 2.2463x; 1.2218x over previous
//
#include <hip/hip_runtime.h>
#include <hip/hip_bf16.h>
#include <math.h>

#define IN_DIM 128
#define OUT_DIM 64
#define NHEAD 4
#define HDIM 16
#define TEMP_INV 2.0f
#define NEG_SLOPE 0.01f

__device__ inline float lrelu(float x) { return x >= 0.f ? x : NEG_SLOPE * x; }

__device__ inline void atomicMaxF(float* addr, float v) {
    if (v >= 0.f) atomicMax((int*)addr, __float_as_int(v));
    else          atomicMin((unsigned int*)addr, __float_as_uint(v));
}

// K1: mask = softmax((logits+gumbel)/TEMP); Wp = diag(mask) @ W; init mAD to -inf
__global__ void k_mask_w(const float* __restrict__ logits, const float* __restrict__ gumbel,
                         const float* __restrict__ W, float* __restrict__ Wp,
                         unsigned* __restrict__ mAD_bits) {
    __shared__ float sh[IN_DIM];
    int t = threadIdx.x;              // 128 threads
    if (t < 8) mAD_bits[t] = 0xFF800000u;  // -inf
    float v = (logits[t] + gumbel[t]) * TEMP_INV;
    sh[t] = v;
    __syncthreads();
    float m = -INFINITY;
    for (int i = 0; i < IN_DIM; ++i) m = fmaxf(m, sh[i]);
    float e = __expf(v - m);
    __syncthreads();
    sh[t] = e;
    __syncthreads();
    float sum = 0.f;
    for (int i = 0; i < IN_DIM; ++i) sum += sh[i];
    float mask = e / sum;
    __syncthreads();
    sh[t] = mask;
    __syncthreads();
    for (int idx = t; idx < IN_DIM * OUT_DIM; idx += blockDim.x)
        Wp[idx] = sh[idx >> 6] * W[idx];
}

// K2: histogram of dst -> deg
__global__ void k_hist(const int* __restrict__ dst, int* __restrict__ deg, int nE) {
    int e = blockIdx.x * blockDim.x + threadIdx.x;
    if (e < nE) atomicAdd(&deg[dst[e]], 1);
}

// K3a: per-block scan (256 thr x 4 elem = 1024/block); cursor = excl-scan within block
__global__ void k_scan1(const int* __restrict__ deg, int* __restrict__ cursor,
                        int* __restrict__ bsum, int n) {
    __shared__ int wsum[4];
    int t = threadIdx.x, lane = t & 63, wid = t >> 6;
    int i0 = blockIdx.x * 1024 + t * 4;
    int a0 = (i0 + 0 < n) ? deg[i0 + 0] : 0;
    int a1 = (i0 + 1 < n) ? deg[i0 + 1] : 0;
    int a2 = (i0 + 2 < n) ? deg[i0 + 2] : 0;
    int a3 = (i0 + 3 < n) ? deg[i0 + 3] : 0;
    int s = a0 + a1 + a2 + a3;
    int x = s;
    #pragma unroll
    for (int off = 1; off < 64; off <<= 1) {
        int y = __shfl_up(x, off, 64);
        if (lane >= off) x += y;
    }
    if (lane == 63) wsum[wid] = x;
    __syncthreads();
    int wbase = 0;
    for (int w = 0; w < wid; ++w) wbase += wsum[w];
    int excl = wbase + x - s;
    if (i0 + 0 < n) cursor[i0 + 0] = excl;
    if (i0 + 1 < n) cursor[i0 + 1] = excl + a0;
    if (i0 + 2 < n) cursor[i0 + 2] = excl + a0 + a1;
    if (i0 + 3 < n) cursor[i0 + 3] = excl + a0 + a1 + a2;
    if (t == 255) bsum[blockIdx.x] = wbase + x;   // block total
}

// K3b: scan block sums (nb <= 256), single block of 256
__global__ void k_scan2(int* __restrict__ bsum, int nb) {
    __shared__ int wsum[4];
    int t = threadIdx.x, lane = t & 63, wid = t >> 6;
    int v = (t < nb) ? bsum[t] : 0;
    int x = v;
    #pragma unroll
    for (int off = 1; off < 64; off <<= 1) {
        int y = __shfl_up(x, off, 64);
        if (lane >= off) x += y;
    }
    if (lane == 63) wsum[wid] = x;
    __syncthreads();
    int wbase = 0;
    for (int w = 0; w < wid; ++w) wbase += wsum[w];
    if (t < nb) bsum[t] = wbase + x - v;          // exclusive
}

// K3c: add block bases
__global__ void k_scan3(int* __restrict__ cursor, const int* __restrict__ bsum, int n) {
    int i = blockIdx.x * blockDim.x + threadIdx.x;
    if (i < n) cursor[i] += bsum[i >> 10];
}

// K4: fill CSR: csr[pos] = src[e], bucketed by dst. cursor ends at off[d+1].
__global__ void k_fill(const int* __restrict__ src, const int* __restrict__ dst,
                       int* __restrict__ cursor, int* __restrict__ csr_src, int nE) {
    int e = blockIdx.x * blockDim.x + threadIdx.x;
    if (e >= nE) return;
    int d = dst[e];
    int pos = atomicAdd(&cursor[d], 1);
    csr_src[pos] = src[e];
}

// K5: h = feat @ Wp; epilogue asrc/adst. 8 rows per wave.
__global__ void k_gemm(const float* __restrict__ feat, const float* __restrict__ Wp,
                       const float* __restrict__ attn_w, float* __restrict__ h,
                       float* __restrict__ asrc, float* __restrict__ adst, int nRows) {
    __shared__ float sW[IN_DIM * OUT_DIM];   // 32 KB
    __shared__ float sA[NHEAD * 2 * HDIM];
    for (int i = threadIdx.x; i < IN_DIM * OUT_DIM; i += blockDim.x) sW[i] = Wp[i];
    if (threadIdx.x < NHEAD * 2 * HDIM) sA[threadIdx.x] = attn_w[threadIdx.x];
    __syncthreads();

    int wave = threadIdx.x >> 6;
    int lane = threadIdx.x & 63;
    int head = lane >> 4, d = lane & 15;
    float aw_s = sA[head * 2 * HDIM + d];
    float aw_d = sA[head * 2 * HDIM + HDIM + d];

    int row0 = (blockIdx.x * 4 + wave) * 8;          // 8 consecutive rows per wave
    if (row0 >= nRows) return;

    float acc[8] = {0.f, 0.f, 0.f, 0.f, 0.f, 0.f, 0.f, 0.f};
    int nr = nRows - row0;
    if (nr > 8) nr = 8;
    const float4* f = (const float4*)(feat + (size_t)row0 * IN_DIM);

    if (nr == 8) {
        #pragma unroll 4
        for (int k4 = 0; k4 < IN_DIM / 4; ++k4) {
            float w0 = sW[(k4 * 4 + 0) * OUT_DIM + lane];
            float w1 = sW[(k4 * 4 + 1) * OUT_DIM + lane];
            float w2 = sW[(k4 * 4 + 2) * OUT_DIM + lane];
            float w3 = sW[(k4 * 4 + 3) * OUT_DIM + lane];
            #pragma unroll
            for (int r = 0; r < 8; ++r) {
                float4 fr = f[r * 32 + k4];
                acc[r] += fr.x * w0 + fr.y * w1 + fr.z * w2 + fr.w * w3;
            }
        }
    } else {
        for (int k4 = 0; k4 < IN_DIM / 4; ++k4) {
            float w0 = sW[(k4 * 4 + 0) * OUT_DIM + lane];
            float w1 = sW[(k4 * 4 + 1) * OUT_DIM + lane];
            float w2 = sW[(k4 * 4 + 2) * OUT_DIM + lane];
            float w3 = sW[(k4 * 4 + 3) * OUT_DIM + lane];
            for (int r = 0; r < nr; ++r) {
                float4 fr = f[r * 32 + k4];
                acc[r] += fr.x * w0 + fr.y * w1 + fr.z * w2 + fr.w * w3;
            }
        }
    }
    for (int r = 0; r < nr; ++r) {
        int row = row0 + r;
        h[(size_t)row * OUT_DIM + lane] = acc[r];
        float v1 = acc[r] * aw_s;
        float v2 = acc[r] * aw_d;
        #pragma unroll
        for (int off = 1; off < HDIM; off <<= 1) {
            v1 += __shfl_xor(v1, off, 64);
            v2 += __shfl_xor(v2, off, 64);
        }
        if (d == 0) {
            asrc[(size_t)row * NHEAD + head] = v1;
            adst[(size_t)row * NHEAD + head] = v2;
        }
    }
}

// K6: per-head global maxima of asrc/adst -> mAD[0..3]=maxA, mAD[4..7]=maxD
__global__ void k_bounds(const float4* __restrict__ asrc, const float4* __restrict__ adst,
                         float* __restrict__ mAD, int nN) {
    int lane = threadIdx.x & 63, wid = threadIdx.x >> 6;
    float4 mA = {-INFINITY, -INFINITY, -INFINITY, -INFINITY};
    float4 mD = {-INFINITY, -INFINITY, -INFINITY, -INFINITY};
    for (int i = blockIdx.x * blockDim.x + threadIdx.x; i < nN; i += gridDim.x * blockDim.x) {
        float4 a = asrc[i], d = adst[i];
        mA.x = fmaxf(mA.x, a.x); mA.y = fmaxf(mA.y, a.y);
        mA.z = fmaxf(mA.z, a.z); mA.w = fmaxf(mA.w, a.w);
        mD.x = fmaxf(mD.x, d.x); mD.y = fmaxf(mD.y, d.y);
        mD.z = fmaxf(mD.z, d.z); mD.w = fmaxf(mD.w, d.w);
    }
    #pragma unroll
    for (int off = 1; off < 64; off <<= 1) {
        mA.x = fmaxf(mA.x, __shfl_xor(mA.x, off, 64));
        mA.y = fmaxf(mA.y, __shfl_xor(mA.y, off, 64));
        mA.z = fmaxf(mA.z, __shfl_xor(mA.z, off, 64));
        mA.w = fmaxf(mA.w, __shfl_xor(mA.w, off, 64));
        mD.x = fmaxf(mD.x, __shfl_xor(mD.x, off, 64));
        mD.y = fmaxf(mD.y, __shfl_xor(mD.y, off, 64));
        mD.z = fmaxf(mD.z, __shfl_xor(mD.z, off, 64));
        mD.w = fmaxf(mD.w, __shfl_xor(mD.w, off, 64));
    }
    __shared__ float red[4][8];
    if (lane == 0) {
        red[wid][0] = mA.x; red[wid][1] = mA.y; red[wid][2] = mA.z; red[wid][3] = mA.w;
        red[wid][4] = mD.x; red[wid][5] = mD.y; red[wid][6] = mD.z; red[wid][7] = mD.w;
    }
    __syncthreads();
    if (threadIdx.x < 8) {
        float v = fmaxf(fmaxf(red[0][threadIdx.x], red[1][threadIdx.x]),
                        fmaxf(red[2][threadIdx.x], red[3][threadIdx.x]));
        atomicMaxF(&mAD[threadIdx.x], v);
    }
}

// K7: fused per-dst-node softmax + weighted gather, global shift (no online max).
// One wave per node; lane = output column. 4-way unrolled independent iterations.
__global__ void k_fused(const int* __restrict__ cursor, const int* __restrict__ csr,
                        const float* __restrict__ asrc, const float* __restrict__ adst,
                        const float* __restrict__ mAD, const float* __restrict__ h,
                        float* __restrict__ out, int nN) {
    int node = blockIdx.x * 4 + (threadIdx.x >> 6);
    if (node >= nN) return;
    int lane = threadIdx.x & 63;
    int head = lane >> 4;
    int start = (node == 0) ? 0 : cursor[node - 1];
    int end = cursor[node];
    float ad = adst[node * 4 + head];
    float B = lrelu(mAD[head] + mAD[4 + head]);   // upper bound on any score of this head
    float acc0 = 0.f, acc1 = 0.f, acc2 = 0.f, acc3 = 0.f;
    float l0 = 0.f, l1 = 0.f, l2 = 0.f, l3 = 0.f;
    for (int e = start; e < end; e += 4) {
        int n = end - e;
        int e1 = n > 1 ? e + 1 : e;
        int e2 = n > 2 ? e + 2 : e;
        int e3 = n > 3 ? e + 3 : e;
        int s0 = csr[e], s1 = csr[e1], s2 = csr[e2], s3 = csr[e3];
        float av0 = asrc[s0 * 4 + head];
        float av1 = asrc[s1 * 4 + head];
        float av2 = asrc[s2 * 4 + head];
        float av3 = asrc[s3 * 4 + head];
        float hv0 = h[(size_t)s0 * OUT_DIM + lane];
        float hv1 = h[(size_t)s1 * OUT_DIM + lane];
        float hv2 = h[(size_t)s2 * OUT_DIM + lane];
        float hv3 = h[(size_t)s3 * OUT_DIM + lane];
        float p0 = __expf(lrelu(av0 + ad) - B);
        float p1 = __expf(lrelu(av1 + ad) - B);
        float p2 = __expf(lrelu(av2 + ad) - B);
        float p3 = __expf(lrelu(av3 + ad) - B);
        p1 = (n > 1) ? p1 : 0.f;
        p2 = (n > 2) ? p2 : 0.f;
        p3 = (n > 3) ? p3 : 0.f;
        acc0 += p0 * hv0; l0 += p0;
        acc1 += p1 * hv1; l1 += p1;
        acc2 += p2 * hv2; l2 += p2;
        acc3 += p3 * hv3; l3 += p3;
    }
    float accs = (acc0 + acc1) + (acc2 + acc3);
    float ls = (l0 + l1) + (l2 + l3);
    out[(size_t)node * OUT_DIM + lane] = (end > start) ? accs / ls : 0.f;
}

extern "C" void kernel_launch(void* const* d_in, const int* in_sizes, int n_in,
                              void* d_out, int out_size, void* d_ws, size_t ws_size,
                              hipStream_t stream) {
    const float* feat   = (const float*)d_in[0];
    const int*   src    = (const int*)  d_in[1];
    const int*   dst    = (const int*)  d_in[2];
    const float* gumbel = (const float*)d_in[3];
    const float* logits = (const float*)d_in[4];
    const float* W      = (const float*)d_in[5];
    const float* attn_w = (const float*)d_in[6];
    float* out = (float*)d_out;

    int N = in_sizes[0] / IN_DIM;
    int E = in_sizes[1];
    int nb = (N + 1023) / 1024;

    float* ws    = (float*)d_ws;
    float* Wp    = ws;                                // 8192
    float* h     = Wp + IN_DIM * OUT_DIM;             // N*64
    float* asrc  = h + (size_t)N * OUT_DIM;           // N*4
    float* adst  = asrc + (size_t)N * NHEAD;          // N*4
    float* mAD   = adst + (size_t)N * NHEAD;          // 8
    int*   deg    = (int*)(mAD + 8);                  // N
    int*   cursor = deg + N;                          // N
    int*   bsum   = cursor + N;                       // nb (<=256)
    int*   csr    = bsum + 256;                       // E

    hipMemsetAsync(deg, 0, (size_t)N * sizeof(int), stream);
    k_mask_w<<<1, 128, 0, stream>>>(logits, gumbel, W, Wp, (unsigned*)mAD);
    k_hist<<<(E + 255) / 256, 256, 0, stream>>>(dst, deg, E);
    k_scan1<<<nb, 256, 0, stream>>>(deg, cursor, bsum, N);
    k_scan2<<<1, 256, 0, stream>>>(bsum, nb);
    k_scan3<<<(N + 255) / 256, 256, 0, stream>>>(cursor, bsum, N);
    k_fill<<<(E + 255) / 256, 256, 0, stream>>>(src, dst, cursor, csr, E);
    k_gemm<<<(N + 31) / 32, 256, 0, stream>>>(feat, Wp, attn_w, h, asrc, adst, N);
    k_bounds<<<128, 256, 0, stream>>>((const float4*)asrc, (const float4*)adst, mAD, N);
    k_fused<<<(N + 3) / 4, 256, 0, stream>>>(cursor, csr, asrc, adst, mAD, h, out, N);
}